// Round 14
// baseline (364.324 us; speedup 1.0000x reference)
//
#include <hip/hip_runtime.h>

typedef __bf16 bf16x8 __attribute__((ext_vector_type(8)));
typedef float  f32x4  __attribute__((ext_vector_type(4)));
typedef float  fvec4  __attribute__((ext_vector_type(4)));

#define NSPEC 8
#define NB    65536
#define NF    256

// ---------------------------------------------------------------------------
// Prologue: W[l][s][in][out] f32  ->  WT[l][s][out][in] bf16   (3 MB in d_ws)
// ---------------------------------------------------------------------------
__global__ __launch_bounds__(256) void wconv_kernel(
    const float* __restrict__ W1, const float* __restrict__ W2,
    const float* __restrict__ W3, __bf16* __restrict__ WT)
{
    __shared__ float tile[32][33];
    int bid = blockIdx.x;
    int l   = bid >> 9;
    int rem = bid & 511;
    int s   = rem >> 6;
    int tt  = rem & 63;
    int ti  = tt >> 3, tj = tt & 7;
    const float* W   = (l == 0) ? W1 : (l == 1) ? W2 : W3;
    const float* ibs = W + (size_t)s * 65536;
    int c  = threadIdx.x & 31;
    int r0 = threadIdx.x >> 5;
#pragma unroll
    for (int k = 0; k < 4; ++k) {
        int r = r0 + k * 8;
        tile[r][c] = ibs[(ti * 32 + r) * 256 + tj * 32 + c];
    }
    __syncthreads();
    __bf16* obs = WT + ((size_t)(l * 8 + s)) * 65536;
#pragma unroll
    for (int k = 0; k < 4; ++k) {
        int r = r0 + k * 8;
        obs[(tj * 32 + r) * 256 + ti * 32 + c] = (__bf16)tile[c][r];
    }
}

// async global->LDS, 16B per lane, literal size (required)
#define GLLD(gp, lp)                                                     \
    __builtin_amdgcn_global_load_lds(                                    \
        (const __attribute__((address_space(1))) char*)(gp),             \
        (__attribute__((address_space(3))) char*)(lp), 16, 0, 0)

// full barrier WITHOUT vmcnt drain: weight prefetch survives.
#define BAR()                                                            \
    do {                                                                 \
        __builtin_amdgcn_sched_barrier(0);                               \
        asm volatile("s_waitcnt lgkmcnt(0)" ::: "memory");               \
        __builtin_amdgcn_s_barrier();                                    \
        __builtin_amdgcn_sched_barrier(0);                               \
    } while (0)

// ---------------------------------------------------------------------------
// Fused MLP, species-split, BM=128: 8 waves (v-quadrant x b-half), weight
// chunk 256v x 32k = 16 KB shared by ALL waves -> weight L2/L3 traffic
// halved vs BM=64 (the measured ~9.5 TB/s weight-fetch BW gate). Depth-3
// counted-vmcnt gll pipeline; one plain s_barrier per step (after each
// wave's lgkmcnt(0), before issuing chunk c+3) closes the cross-wave
// buffer-reuse hazard without draining prefetch.
// ---------------------------------------------------------------------------
__global__ __launch_bounds__(512, 2) void mlp_kernel(
    const float* __restrict__ bIn, const float* __restrict__ b1,
    const float* __restrict__ b2,  const float* __restrict__ b3,
    const float* __restrict__ W4,  const float* __restrict__ b4,
    const __bf16* __restrict__ WT, float* __restrict__ P)
{
    __shared__ __align__(16) __bf16 act[128 * 256];  // 64 KB act, in-place
    __shared__ __align__(16) char  wlds[3][16384];   // 3 x 16KB weight chunks

    const int t     = threadIdx.x;
    const int lane  = t & 63;
    const int wave  = t >> 6;          // 0..7
    const int l15   = lane & 15;
    const int g     = lane >> 4;       // 0..3
    const int vbase = (wave & 3) * 64; // v-quadrant
    const int bbase = (wave >> 2) * 64;// b-half
    const int s     = blockIdx.x >> 9;
    const int row0  = (blockIdx.x & 511) * 128;
    const int swzB  = l15 << 4;
    char* const pA  = (char*)act;

    // gll: wave stages chunk rows [wave*32, wave*32+32), 2 instrs x 1KB.
    // lane holds row v = wave*32+i*16+(lane>>2), global quarter
    // q = (lane&3) ^ ((v>>1)&3); LDS dest linear -> slot lane&3.
    int gll_off[2];
#pragma unroll
    for (int i = 0; i < 2; ++i) {
        int v = wave * 32 + i * 16 + (lane >> 2);
        int q = (lane & 3) ^ ((v >> 1) & 3);
        gll_off[i] = v * 512 + q * 16;
    }

    const char* const wt0 = (const char*)(WT + ((size_t)(0 * 8 + s) << 16));
    const char* const wt1 = (const char*)(WT + ((size_t)(1 * 8 + s) << 16));
    const char* const wt2 = (const char*)(WT + ((size_t)(2 * 8 + s) << 16));

#define ISSUE_CHUNK(wtb, gci)                                            \
    do {                                                                 \
        char* lp0 = (char*)&wlds[(gci) % 3][wave * 2048];                \
        GLLD((wtb) + gll_off[0] + ((gci) & 7) * 64, lp0);                \
        GLLD((wtb) + gll_off[1] + ((gci) & 7) * 64, lp0 + 1024);         \
    } while (0)

    // ---- preload biases for all 3 layers
    fvec4 bias[3][4];
#pragma unroll
    for (int l = 0; l < 3; ++l) {
        const float* bl = (l == 0 ? b1 : l == 1 ? b2 : b3) + s * 256;
#pragma unroll
        for (int m = 0; m < 4; ++m)
            bias[l][m] = *(const fvec4*)(bl + vbase + m * 16 + g * 4);
    }

    // ---- stage b[s][row0..row0+127][:] fp32 -> bf16 into act (swizzled)
    const float* src = bIn + ((size_t)s * NB + row0) * NF;
#pragma unroll
    for (int it = 0; it < 16; ++it) {
        int idx = it * 2048 + t * 4;
        int r = idx >> 8;              // 0..127
        int f = idx & 255;
        fvec4 v = __builtin_nontemporal_load((const fvec4*)(src + idx));
        union { __bf16 h[4]; unsigned long long q; } pk;
        pk.h[0] = (__bf16)v[0]; pk.h[1] = (__bf16)v[1];
        pk.h[2] = (__bf16)v[2]; pk.h[3] = (__bf16)v[3];
        *(unsigned long long*)(pA + r * 512 + ((f * 2) ^ ((r & 15) << 4))) = pk.q;
    }

    // ---- prime the weight pipeline: 3 chunks (6 glls/wave) in flight
    ISSUE_CHUNK(wt0, 0);
    ISSUE_CHUNK(wt0, 1);
    ISSUE_CHUNK(wt0, 2);
    BAR();   // act ready; glls fly over (no vmcnt drain)

#pragma unroll
    for (int l = 0; l < 3; ++l) {
        f32x4 acc[4][4];
#pragma unroll
        for (int m = 0; m < 4; ++m)
#pragma unroll
            for (int n = 0; n < 4; ++n)
                acc[m][n] = (f32x4){0.f, 0.f, 0.f, 0.f};

#pragma unroll
        for (int ks = 0; ks < 8; ++ks) {
            const int c = l * 8 + ks;          // chunk consumed this step
            // require only chunk c's arrival (2 glls/chunk/wave)
            if (c <= 21)      asm volatile("s_waitcnt vmcnt(4)" ::: "memory");
            else if (c == 22) asm volatile("s_waitcnt vmcnt(2)" ::: "memory");
            else              asm volatile("s_waitcnt vmcnt(0)" ::: "memory");

            const char* wbuf = (const char*)wlds[c % 3];
            bf16x8 af[4], bfr[4];
#pragma unroll
            for (int m = 0; m < 4; ++m) {
                int row = vbase + m * 16 + l15;
                af[m] = *(const bf16x8*)(wbuf + row * 64 + ((g ^ ((row >> 1) & 3)) << 4));
            }
#pragma unroll
            for (int n = 0; n < 4; ++n)
                bfr[n] = *(const bf16x8*)(pA + (bbase + n * 16 + l15) * 512 + ((ks * 64 + g * 16) ^ swzB));

            __builtin_amdgcn_s_setprio(1);
#pragma unroll
            for (int m = 0; m < 4; ++m)
#pragma unroll
                for (int n = 0; n < 4; ++n)
                    acc[m][n] = __builtin_amdgcn_mfma_f32_16x16x32_bf16(af[m], bfr[n], acc[m][n], 0, 0, 0);
            __builtin_amdgcn_s_setprio(0);

            // own reads retired...
            asm volatile("s_waitcnt lgkmcnt(0)" ::: "memory");
            // ...and ALL waves' reads retired (they hit lgkmcnt before this):
            __builtin_amdgcn_s_barrier();      // no vmcnt drain attached
            const int gci = c + 3;             // refill buf c%3, now safe
            if (gci < 24) {
                const char* wtc = (gci < 8) ? wt0 : (gci < 16) ? wt1 : wt2;
                ISSUE_CHUNK(wtc, gci);
            }
            __builtin_amdgcn_sched_barrier(0);
        }

        BAR();   // all act reads complete before in-place update

        // epilogue: +bias, leaky, cvt bf16, packed 8B write (own b-half)
#pragma unroll
        for (int m = 0; m < 4; ++m) {
            int vbyte = (vbase + m * 16 + g * 4) * 2;
#pragma unroll
            for (int n = 0; n < 4; ++n) {
                union { __bf16 h[4]; unsigned long long q; } pk;
#pragma unroll
                for (int j = 0; j < 4; ++j) {
                    float x = acc[m][n][j] + bias[l][m][j];
                    x = (x >= 0.f) ? x : 0.1f * x;
                    pk.h[j] = (__bf16)x;
                }
                *(unsigned long long*)(pA + (bbase + n * 16 + l15) * 512 + (vbyte ^ swzB)) = pk.q;
            }
        }
        BAR();
    }

    // ---- layer 4: A_s[row] = dot(act3[row], w4[s]) + b4[s] -> partial P
    const int r4   = t >> 2;           // 0..127
    const int u0   = (t & 3) * 64;
    const int swz4 = (r4 & 15) << 4;
    const float* w4s = W4 + s * 256 + u0;
    float part = 0.f;
#pragma unroll
    for (int i = 0; i < 8; ++i) {
        bf16x8 x = *(const bf16x8*)(pA + r4 * 512 + (((u0 + i * 8) * 2) ^ swz4));
        fvec4 wlo = *(const fvec4*)(w4s + i * 8);
        fvec4 whi = *(const fvec4*)(w4s + i * 8 + 4);
        part += (float)x[0] * wlo[0] + (float)x[1] * wlo[1] +
                (float)x[2] * wlo[2] + (float)x[3] * wlo[3] +
                (float)x[4] * whi[0] + (float)x[5] * whi[1] +
                (float)x[6] * whi[2] + (float)x[7] * whi[3];
    }
    part += __shfl_xor(part, 1);
    part += __shfl_xor(part, 2);
    if ((t & 3) == 0) P[(size_t)s * NB + row0 + r4] = part + b4[s];
}

// ---------------------------------------------------------------------------
// Final: out[i] = sigmoid(sum_s P[s][i])
// ---------------------------------------------------------------------------
__global__ __launch_bounds__(256) void reduce_kernel(
    const float* __restrict__ P, float* __restrict__ out)
{
    int i = blockIdx.x * 256 + threadIdx.x;
    float a = 0.f;
#pragma unroll
    for (int sp = 0; sp < NSPEC; ++sp) a += P[(size_t)sp * NB + i];
    out[i] = 1.f / (1.f + __expf(-a));
}

extern "C" void kernel_launch(void* const* d_in, const int* in_sizes, int n_in,
                              void* d_out, int out_size, void* d_ws, size_t ws_size,
                              hipStream_t stream)
{
    const float* bIn = (const float*)d_in[0];
    const float* W1  = (const float*)d_in[1];
    const float* b1  = (const float*)d_in[2];
    const float* W2  = (const float*)d_in[3];
    const float* b2  = (const float*)d_in[4];
    const float* W3  = (const float*)d_in[5];
    const float* b3  = (const float*)d_in[6];
    const float* W4  = (const float*)d_in[7];
    const float* b4  = (const float*)d_in[8];
    __bf16* WT = (__bf16*)d_ws;                       // 3 MB
    float*  P  = (float*)((char*)d_ws + (3u << 20));  // 2 MB partials

    wconv_kernel<<<1536, 256, 0, stream>>>(W1, W2, W3, WT);
    mlp_kernel<<<4096, 512, 0, stream>>>(bIn, b1, b2, b3, W4, b4, WT, P);
    reduce_kernel<<<NB / 256, 256, 0, stream>>>(P, (float*)d_out);
}

// Round 15
// 327.759 us; speedup vs baseline: 1.1116x; 1.1116x over previous
//
#include <hip/hip_runtime.h>

typedef __bf16 bf16x8 __attribute__((ext_vector_type(8)));
typedef float  f32x4  __attribute__((ext_vector_type(4)));
typedef float  fvec4  __attribute__((ext_vector_type(4)));

#define NSPEC 8
#define NB    65536
#define NF    256

// ---------------------------------------------------------------------------
// Prologue: W[l][s][in][out] f32  ->  WT[l][s][out][in] bf16   (3 MB in d_ws)
// ---------------------------------------------------------------------------
__global__ __launch_bounds__(256) void wconv_kernel(
    const float* __restrict__ W1, const float* __restrict__ W2,
    const float* __restrict__ W3, __bf16* __restrict__ WT)
{
    __shared__ float tile[32][33];
    int bid = blockIdx.x;
    int l   = bid >> 9;
    int rem = bid & 511;
    int s   = rem >> 6;
    int tt  = rem & 63;
    int ti  = tt >> 3, tj = tt & 7;
    const float* W   = (l == 0) ? W1 : (l == 1) ? W2 : W3;
    const float* ibs = W + (size_t)s * 65536;
    int c  = threadIdx.x & 31;
    int r0 = threadIdx.x >> 5;
#pragma unroll
    for (int k = 0; k < 4; ++k) {
        int r = r0 + k * 8;
        tile[r][c] = ibs[(ti * 32 + r) * 256 + tj * 32 + c];
    }
    __syncthreads();
    __bf16* obs = WT + ((size_t)(l * 8 + s)) * 65536;
#pragma unroll
    for (int k = 0; k < 4; ++k) {
        int r = r0 + k * 8;
        obs[(tj * 32 + r) * 256 + ti * 32 + c] = (__bf16)tile[c][r];
    }
}

// async global->LDS, 16B per lane, literal size (required)
#define GLLD(gp, lp)                                                     \
    __builtin_amdgcn_global_load_lds(                                    \
        (const __attribute__((address_space(1))) char*)(gp),             \
        (__attribute__((address_space(3))) char*)(lp), 16, 0, 0)

// full barrier WITHOUT vmcnt drain: weight prefetch survives.
#define BAR()                                                            \
    do {                                                                 \
        __builtin_amdgcn_sched_barrier(0);                               \
        asm volatile("s_waitcnt lgkmcnt(0)" ::: "memory");               \
        __builtin_amdgcn_s_barrier();                                    \
        __builtin_amdgcn_sched_barrier(0);                               \
    } while (0)

// ---------------------------------------------------------------------------
// Fused MLP, species-split, r12 shape (BM=64, 4 waves, wave-private weight
// planes, depth-3 gll ring) + m201-style READ-AHEAD: step ks ds_reads the
// fragments for step ks+1 into the alternate register set, then MFMAs on the
// set read LAST step (its reads long retired -> no LDS latency on the MFMA
// path). Buffer-reuse guard is a counted lgkmcnt(8) (not a drain); gll
// refill of buf c%3 follows it. No extra barriers (planes are wave-private).
// ---------------------------------------------------------------------------
__global__ __launch_bounds__(256, 2) void mlp_kernel(
    const float* __restrict__ bIn, const float* __restrict__ b1,
    const float* __restrict__ b2,  const float* __restrict__ b3,
    const float* __restrict__ W4,  const float* __restrict__ b4,
    const __bf16* __restrict__ WT, float* __restrict__ P)
{
    __shared__ __align__(16) __bf16 act[64 * 256];   // 32 KB act, in-place
    __shared__ __align__(16) char  wlds[3][16384];   // 3 x 16KB weight chunks

    const int t    = threadIdx.x;
    const int lane = t & 63;
    const int wave = t >> 6;          // 0..3, owns v-range [wave*64, wave*64+64)
    const int l15  = lane & 15;
    const int g    = lane >> 4;       // 0..3
    const int wv   = wave * 64;
    const int s    = blockIdx.x >> 10;
    const int row0 = (blockIdx.x & 1023) * 64;
    const int swzB = l15 << 4;
    char* const pA = (char*)act;

    // per-lane global byte offsets: instr i covers v = wv+i*16+lane/4,
    // slot lane&3 holds global quarter q = slot ^ ((v>>1)&3) (same 64B line).
    int gll_off[4];
#pragma unroll
    for (int i = 0; i < 4; ++i) {
        int v = wv + i * 16 + (lane >> 2);
        int q = (lane & 3) ^ ((v >> 1) & 3);
        gll_off[i] = v * 512 + q * 16;
    }

    const char* const wt0 = (const char*)(WT + ((size_t)(0 * 8 + s) << 16));
    const char* const wt1 = (const char*)(WT + ((size_t)(1 * 8 + s) << 16));
    const char* const wt2 = (const char*)(WT + ((size_t)(2 * 8 + s) << 16));

#define ISSUE_CHUNK(wtb, gci)                                            \
    do {                                                                 \
        char* lp0 = (char*)&wlds[(gci) % 3][wave * 4096];                \
        GLLD((wtb) + gll_off[0] + ((gci) & 7) * 64, lp0);                \
        GLLD((wtb) + gll_off[1] + ((gci) & 7) * 64, lp0 + 1024);         \
        GLLD((wtb) + gll_off[2] + ((gci) & 7) * 64, lp0 + 2048);         \
        GLLD((wtb) + gll_off[3] + ((gci) & 7) * 64, lp0 + 3072);         \
    } while (0)

#define READ_SET(AF, BF, gci, kslice)                                    \
    do {                                                                 \
        const char* wbuf_ = (const char*)wlds[(gci) % 3];                \
        _Pragma("unroll")                                                \
        for (int m_ = 0; m_ < 4; ++m_) {                                 \
            int row_ = wv + m_ * 16 + l15;                               \
            AF[m_] = *(const bf16x8*)(wbuf_ + row_ * 64 +                \
                                      ((g ^ ((row_ >> 1) & 3)) << 4));   \
        }                                                                \
        _Pragma("unroll")                                                \
        for (int n_ = 0; n_ < 4; ++n_)                                   \
            BF[n_] = *(const bf16x8*)(pA + (n_ * 16 + l15) * 512 +       \
                                      (((kslice) * 64 + g * 16) ^ swzB));\
    } while (0)

#define MFMA_SET(AF, BF)                                                 \
    do {                                                                 \
        __builtin_amdgcn_s_setprio(1);                                   \
        _Pragma("unroll")                                                \
        for (int m_ = 0; m_ < 4; ++m_)                                   \
            _Pragma("unroll")                                            \
            for (int n_ = 0; n_ < 4; ++n_)                               \
                acc[m_][n_] = __builtin_amdgcn_mfma_f32_16x16x32_bf16(   \
                    AF[m_], BF[n_], acc[m_][n_], 0, 0, 0);               \
        __builtin_amdgcn_s_setprio(0);                                   \
    } while (0)

    // ---- preload biases for all 3 layers (loop vmem must be glls only)
    fvec4 bias[3][4];
#pragma unroll
    for (int l = 0; l < 3; ++l) {
        const float* bl = (l == 0 ? b1 : l == 1 ? b2 : b3) + s * 256;
#pragma unroll
        for (int m = 0; m < 4; ++m)
            bias[l][m] = *(const fvec4*)(bl + wv + m * 16 + g * 4);
    }

    // ---- stage b[s][row0..row0+63][:] fp32 -> bf16 into act (swizzled)
    const float* src = bIn + ((size_t)s * NB + row0) * NF;
#pragma unroll
    for (int it = 0; it < 16; ++it) {
        int flat = it * 1024 + t * 4;
        int r = flat >> 8;
        int f = flat & 255;
        fvec4 v = __builtin_nontemporal_load((const fvec4*)(src + flat));
        union { __bf16 h[4]; unsigned long long q; } pk;
        pk.h[0] = (__bf16)v[0]; pk.h[1] = (__bf16)v[1];
        pk.h[2] = (__bf16)v[2]; pk.h[3] = (__bf16)v[3];
        *(unsigned long long*)(pA + r * 512 + ((f * 2) ^ ((r & 15) << 4))) = pk.q;
    }

    // ---- prime the weight pipeline: 3 chunks in flight
    ISSUE_CHUNK(wt0, 0);
    ISSUE_CHUNK(wt0, 1);
    ISSUE_CHUNK(wt0, 2);
    BAR();   // act ready; glls fly over (no vmcnt drain)

#pragma unroll
    for (int l = 0; l < 3; ++l) {
        const int c0 = l * 8;
        f32x4 acc[4][4];
#pragma unroll
        for (int m = 0; m < 4; ++m)
#pragma unroll
            for (int n = 0; n < 4; ++n)
                acc[m][n] = (f32x4){0.f, 0.f, 0.f, 0.f};

        // layer prologue: chunk c0 arrived (up to 2 more outstanding)
        bf16x8 afX[4], bfX[4], afY[4], bfY[4];
        asm volatile("s_waitcnt vmcnt(8)" ::: "memory");
        READ_SET(afX, bfX, c0, 0);

#pragma unroll
        for (int ks = 0; ks < 8; ++ks) {
            const int c = c0 + ks;             // chunk consumed this step
            if (ks < 7) {
                // read NEXT step's fragments (chunk c+1 must have arrived;
                // chunk c+2 may stay in flight)
                if (c <= 21) asm volatile("s_waitcnt vmcnt(4)" ::: "memory");
                else         asm volatile("s_waitcnt vmcnt(0)" ::: "memory");
                if ((ks & 1) == 0) READ_SET(afY, bfY, c + 1, ks + 1);
                else               READ_SET(afX, bfX, c + 1, ks + 1);
                // counted guard: allow the 8 just-issued reads outstanding,
                // require chunk c's reads (last step) retired
                asm volatile("s_waitcnt lgkmcnt(8)" ::: "memory");
            } else {
                asm volatile("s_waitcnt lgkmcnt(0)" ::: "memory");
            }
            const int gci = c + 3;             // refill buf c%3 (now safe)
            if (gci <= 23) {
                const char* wtc = (gci < 8) ? wt0 : (gci < 16) ? wt1 : wt2;
                ISSUE_CHUNK(wtc, gci);
            }
            __builtin_amdgcn_sched_barrier(0);
            // MFMAs on the set read LAST step: operands long since in regs
            if ((ks & 1) == 0) MFMA_SET(afX, bfX);
            else               MFMA_SET(afY, bfY);
            __builtin_amdgcn_sched_barrier(0);
        }

        BAR();   // all act reads complete before in-place update

        // epilogue: +bias, leaky, cvt bf16, packed 8B write
#pragma unroll
        for (int m = 0; m < 4; ++m) {
            int vbyte = (wv + m * 16 + g * 4) * 2;
#pragma unroll
            for (int n = 0; n < 4; ++n) {
                union { __bf16 h[4]; unsigned long long q; } pk;
#pragma unroll
                for (int j = 0; j < 4; ++j) {
                    float x = acc[m][n][j] + bias[l][m][j];
                    x = (x >= 0.f) ? x : 0.1f * x;
                    pk.h[j] = (__bf16)x;
                }
                *(unsigned long long*)(pA + (n * 16 + l15) * 512 + (vbyte ^ swzB)) = pk.q;
            }
        }
        BAR();
    }

    // ---- layer 4: A_s[row] = dot(act3[row], w4[s]) + b4[s] -> partial P
    const int r4   = t >> 2;
    const int u0   = (t & 3) * 64;
    const int swz4 = (r4 & 15) << 4;
    const float* w4s = W4 + s * 256 + u0;
    float part = 0.f;
#pragma unroll
    for (int i = 0; i < 8; ++i) {
        bf16x8 x = *(const bf16x8*)(pA + r4 * 512 + (((u0 + i * 8) * 2) ^ swz4));
        fvec4 wlo = *(const fvec4*)(w4s + i * 8);
        fvec4 whi = *(const fvec4*)(w4s + i * 8 + 4);
        part += (float)x[0] * wlo[0] + (float)x[1] * wlo[1] +
                (float)x[2] * wlo[2] + (float)x[3] * wlo[3] +
                (float)x[4] * whi[0] + (float)x[5] * whi[1] +
                (float)x[6] * whi[2] + (float)x[7] * whi[3];
    }
    part += __shfl_xor(part, 1);
    part += __shfl_xor(part, 2);
    if ((t & 3) == 0) P[(size_t)s * NB + row0 + r4] = part + b4[s];
}

// ---------------------------------------------------------------------------
// Final: out[i] = sigmoid(sum_s P[s][i])
// ---------------------------------------------------------------------------
__global__ __launch_bounds__(256) void reduce_kernel(
    const float* __restrict__ P, float* __restrict__ out)
{
    int i = blockIdx.x * 256 + threadIdx.x;
    float a = 0.f;
#pragma unroll
    for (int sp = 0; sp < NSPEC; ++sp) a += P[(size_t)sp * NB + i];
    out[i] = 1.f / (1.f + __expf(-a));
}

extern "C" void kernel_launch(void* const* d_in, const int* in_sizes, int n_in,
                              void* d_out, int out_size, void* d_ws, size_t ws_size,
                              hipStream_t stream)
{
    const float* bIn = (const float*)d_in[0];
    const float* W1  = (const float*)d_in[1];
    const float* b1  = (const float*)d_in[2];
    const float* W2  = (const float*)d_in[3];
    const float* b2  = (const float*)d_in[4];
    const float* W3  = (const float*)d_in[5];
    const float* b3  = (const float*)d_in[6];
    const float* W4  = (const float*)d_in[7];
    const float* b4  = (const float*)d_in[8];
    __bf16* WT = (__bf16*)d_ws;                       // 3 MB
    float*  P  = (float*)((char*)d_ws + (3u << 20));  // 2 MB partials

    wconv_kernel<<<1536, 256, 0, stream>>>(W1, W2, W3, WT);
    mlp_kernel<<<8192, 256, 0, stream>>>(bIn, b1, b2, b3, W4, b4, WT, P);
    reduce_kernel<<<NB / 256, 256, 0, stream>>>(P, (float*)d_out);
}